// Round 24
// baseline (257.217 us; speedup 1.0000x reference)
//
#include <hip/hip_runtime.h>
#include <cstdint>

#define K_NE 16
constexpr int B = 8, N = 2048, F = 128;
constexpr size_t NSEND = (size_t)B * N;                 // 16384 sender rows
constexpr size_t EDGE_FLOATS = NSEND * K_NE * 256;      // 67,108,864
constexpr size_t HALF_ELEMS = NSEND * F;                // per staging matrix
constexpr int SPB = 16;                                 // senders per block

typedef _Float16 half8 __attribute__((ext_vector_type(8)));
typedef _Float16 half2v __attribute__((ext_vector_type(2)));
typedef float floatx4 __attribute__((ext_vector_type(4)));

#define SCALE 2048.0f                    // exact power of 2
#define INV_SC2 2.384185791015625e-07f   // 2^-22, exact
#define F16_MIN_NORM 6.103515625e-05f    // 2^-14

// ------------ K0: fused row norms + f32 -> scaled (f16 hi,lo) convert -------
// (r18 version, proven; one-shot global conversion — no per-block redundancy)
__global__ __launch_bounds__(256) void prep_kernel(const float* __restrict__ S,
                                                   const float* __restrict__ Rv,
                                                   float* __restrict__ x2,
                                                   float* __restrict__ y2,
                                                   _Float16* __restrict__ SH,
                                                   _Float16* __restrict__ SL,
                                                   _Float16* __restrict__ RH,
                                                   _Float16* __restrict__ RL) {
    const int tid = blockIdx.x * 256 + threadIdx.x;
    const int w = tid >> 6, lane = tid & 63;           // w = 0..32767
    const bool isR = w >= (int)NSEND;
    const int row = isR ? w - (int)NSEND : w;
    const float* X = isR ? Rv : S;
    _Float16* H = isR ? RH : SH;
    _Float16* L = isR ? RL : SL;
    float* nrm = isR ? y2 : x2;

    const float2 v = ((const float2*)(X + (size_t)row * F))[lane];
    float s = v.x * v.x + v.y * v.y;
    #pragma unroll
    for (int off = 32; off; off >>= 1) s += __shfl_xor(s, off);
    if (lane == 0) nrm[row] = s;

    const float a0 = v.x * SCALE, a1 = v.y * SCALE;
    _Float16 h0 = (_Float16)a0;
    if (fabsf((float)h0) < F16_MIN_NORM) h0 = (_Float16)0.0f;
    _Float16 l0 = (_Float16)(a0 - (float)h0);
    if (fabsf((float)l0) < F16_MIN_NORM) l0 = (_Float16)0.0f;
    _Float16 h1 = (_Float16)a1;
    if (fabsf((float)h1) < F16_MIN_NORM) h1 = (_Float16)0.0f;
    _Float16 l1 = (_Float16)(a1 - (float)h1);
    if (fabsf((float)l1) < F16_MIN_NORM) l1 = (_Float16)0.0f;
    half2v hv = {h0, h1}, lv = {l0, l1};
    *(half2v*)(H + (size_t)row * F + lane * 2) = hv;
    *(half2v*)(L + (size_t)row * F + lane * 2) = lv;
}

#define KEYC(U, C) ((C) == 0 ? (U).x : (C) == 1 ? (U).y : (C) == 2 ? (U).z : (U).w)

// ---- K1: FUSED score + top-16 + edges (+ idx emit) -------------------------
// Block = 16 waves x 64, owns 16 senders x all 2048 receivers of one batch.
// Phase 1: wave wv computes cols [wv*128, wv*128+128) from PRE-CONVERTED
// halves (zero conversion VALU; B working set 4.2 MB/batch, L2/L3-hot);
// MFMA chain (ks ascending, hh->hl->lh), unscale, key packing identical to
// r18 -> bit-identical selection. Keys to 128 KB LDS.
// Phase 2: wave wv selects row wv (r18 exact path), writes 16 edge rows and
// the 16 indices to ws. Conn matrix written by a later kernel (staging in the
// conn region must be consumed first).
__global__ __launch_bounds__(1024) void fused_kernel(const float* __restrict__ S,
                                                     const float* __restrict__ Rv,
                                                     const _Float16* __restrict__ SH,
                                                     const _Float16* __restrict__ SL,
                                                     const _Float16* __restrict__ RH,
                                                     const _Float16* __restrict__ RL,
                                                     const float* __restrict__ x2,
                                                     const float* __restrict__ y2,
                                                     float* __restrict__ edges_out,
                                                     int* __restrict__ idxb) {
    __shared__ uint32_t keys[SPB][N];     // 128 KB
    __shared__ double candbuf[16][64];    // 8 KB
    const int t = threadIdx.x, lane = t & 63, wv = t >> 6;   // wv 0..15
    const int blk = blockIdx.x;           // 0..1023
    const int bz = blk >> 7;              // batch
    const int sg0 = (blk & 127) * SPB;    // batch-local sender base
    const int lr = lane & 15, kgrp = lane >> 4;
    const double MAGIC = 4503599627370496.0;   // 2^52

    const float* x2b = x2 + bz * N;
    const float* y2b = y2 + bz * N;

    // ---- A fragments: 16 senders x K=128 from staged halves ---------------
    half8 ah[4], al[4];
    {
        const _Float16* aH = SH + ((size_t)(bz * N + sg0 + lr)) * F;
        const _Float16* aL = SL + ((size_t)(bz * N + sg0 + lr)) * F;
        #pragma unroll
        for (int ks = 0; ks < 4; ++ks) {
            const int k0 = ks * 32 + kgrp * 8;
            ah[ks] = *(const half8*)(aH + k0);
            al[ks] = *(const half8*)(aL + k0);
        }
    }
    float xr[4];
    #pragma unroll
    for (int r = 0; r < 4; ++r) xr[r] = x2b[sg0 + kgrp * 4 + r];

    // ---- phase 1: 8 col-tiles of 16 per wave ------------------------------
    #pragma unroll 1
    for (int ct = 0; ct < 8; ++ct) {
        const int col0 = wv * 128 + ct * 16;
        const _Float16* bH = RH + (size_t)(bz * N + col0 + lr) * F;
        const _Float16* bL = RL + (size_t)(bz * N + col0 + lr) * F;
        floatx4 acc = {0.f, 0.f, 0.f, 0.f};
        #pragma unroll
        for (int ks = 0; ks < 4; ++ks) {
            const int k0 = ks * 32 + kgrp * 8;
            const half8 bh = *(const half8*)(bH + k0);
            const half8 bl = *(const half8*)(bL + k0);
            acc = __builtin_amdgcn_mfma_f32_16x16x32_f16(ah[ks], bh, acc, 0, 0, 0);
            acc = __builtin_amdgcn_mfma_f32_16x16x32_f16(ah[ks], bl, acc, 0, 0, 0);
            acc = __builtin_amdgcn_mfma_f32_16x16x32_f16(al[ks], bh, acc, 0, 0, 0);
        }
        const float yv = y2b[col0 + lr];
        #pragma unroll
        for (int r = 0; r < 4; ++r) {
            const float d = acc[r] * INV_SC2;   // exact unscale
            const float sc = fabsf((-2.0f * d + xr[r]) + yv);
            keys[kgrp * 4 + r][col0 + lr] = __float_as_uint(sc);
        }
    }
    __syncthreads();

    // ---- phase 2: wave wv -> row wv (r18 exact select) --------------------
    const int g = bz * N + sg0 + wv;      // global sender id
    double* cbuf = candbuf[wv];
    const uint4* krow = (const uint4*)keys[wv];

    uint4 u[8];
    uint32_t mk = 0xFFFFFFFFu;
    #pragma unroll
    for (int jj = 0; jj < 8; ++jj) {
        u[jj] = krow[jj * 64 + lane];
        mk = mk < u[jj].x ? mk : u[jj].x;
        mk = mk < u[jj].y ? mk : u[jj].y;
        mk = mk < u[jj].z ? mk : u[jj].z;
        mk = mk < u[jj].w ? mk : u[jj].w;
    }

    uint32_t v = mk;
    #pragma unroll
    for (int k = 2; k <= 64; k <<= 1) {
        #pragma unroll
        for (int j = k >> 1; j >= 1; j >>= 1) {
            uint32_t o = (uint32_t)__shfl_xor((int)v, j);
            const bool take_min = (((lane & j) == 0) == ((lane & k) == 0));
            const uint32_t mn = v < o ? v : o;
            const uint32_t mx = v < o ? o : v;
            v = take_min ? mn : mx;
        }
    }
    const uint32_t T16 = (uint32_t)__shfl((int)v, 15);

    int myc = 0;
    #pragma unroll
    for (int jj = 0; jj < 8; ++jj)
        #pragma unroll
        for (int c = 0; c < 4; ++c)
            myc += (KEYC(u[jj], c) <= T16) ? 1 : 0;
    int off = myc;
    #pragma unroll
    for (int d = 1; d < 64; d <<= 1) {
        const int o = __shfl_up(off, d);
        if (lane >= d) off += o;
    }
    const int total = __shfl(off, 63);
    const int base = off - myc;

    int ixs[16];
    if (total <= 64) {
        int p = base;
        #pragma unroll
        for (int jj = 0; jj < 8; ++jj)
            #pragma unroll
            for (int c = 0; c < 4; ++c) {
                const uint32_t key = KEYC(u[jj], c);
                if (key <= T16) {
                    cbuf[p] = (double)key * 2048.0 + (double)(jj * 256 + lane * 4 + c);
                    ++p;
                }
            }
        double d = (lane < total) ? cbuf[lane] : 1e300;
        #pragma unroll
        for (int k = 2; k <= 64; k <<= 1) {
            #pragma unroll
            for (int j = k >> 1; j >= 1; j >>= 1) {
                const double o = __shfl_xor(d, j);
                const bool take_min = (((lane & j) == 0) == ((lane & k) == 0));
                d = take_min ? fmin(d, o) : fmax(d, o);
            }
        }
        const int myidx = (int)(__double_as_longlong(d + MAGIC) & 2047);
        #pragma unroll
        for (int e = 0; e < 16; ++e) ixs[e] = __shfl(myidx, e);
    } else {
        // ---- fallback (tie storm): register-masked iterative extraction --
        uint32_t fk = 0xFFFFFFFFu, fi = 0;
        #pragma unroll
        for (int jj = 0; jj < 8; ++jj) {
            const uint32_t bse = (uint32_t)(jj * 256 + lane * 4);
            if (u[jj].x < fk) { fk = u[jj].x; fi = bse; }
            if (u[jj].y < fk) { fk = u[jj].y; fi = bse + 1; }
            if (u[jj].z < fk) { fk = u[jj].z; fi = bse + 2; }
            if (u[jj].w < fk) { fk = u[jj].w; fi = bse + 3; }
        }
        #pragma unroll
        for (int it = 0; it < 16; ++it) {
            const uint32_t ck = fk, ci = fi;
            uint32_t gk = fk, gi = fi;
            #pragma unroll
            for (int o2 = 32; o2; o2 >>= 1) {
                uint32_t ok = (uint32_t)__shfl_xor((int)gk, o2);
                uint32_t oi = (uint32_t)__shfl_xor((int)gi, o2);
                if (ok < gk || (ok == gk && oi < gi)) { gk = ok; gi = oi; }
            }
            ixs[it] = (int)gi;
            if (ck == gk && ci == gi) {
                const int djj = (int)(gi >> 8), dc = (int)(gi & 3);
                #pragma unroll
                for (int jj = 0; jj < 8; ++jj)
                    if (jj == djj) {
                        if (dc == 0) u[jj].x = 0xFFFFFFFFu;
                        else if (dc == 1) u[jj].y = 0xFFFFFFFFu;
                        else if (dc == 2) u[jj].z = 0xFFFFFFFFu;
                        else u[jj].w = 0xFFFFFFFFu;
                    }
                fk = 0xFFFFFFFFu; fi = 0;
                #pragma unroll
                for (int jj = 0; jj < 8; ++jj) {
                    const uint32_t bse = (uint32_t)(jj * 256 + lane * 4);
                    if (u[jj].x < fk) { fk = u[jj].x; fi = bse; }
                    if (u[jj].y < fk) { fk = u[jj].y; fi = bse + 1; }
                    if (u[jj].z < fk) { fk = u[jj].z; fi = bse + 2; }
                    if (u[jj].w < fk) { fk = u[jj].w; fi = bse + 3; }
                }
            }
        }
    }

    // ---- ranks: output slot = ascending receiver-index position -----------
    int rank[16];
    #pragma unroll
    for (int e = 0; e < 16; ++e) {
        int r = 0;
        #pragma unroll
        for (int f = 0; f < 16; ++f) r += (ixs[f] < ixs[e]) ? 1 : 0;
        rank[e] = r;
    }

    // ---- emit indices (order irrelevant for conn; rank-sorted for tidiness)
    int myix = 0, myrk = 0;
    #pragma unroll
    for (int e = 0; e < 16; ++e)
        if (lane == e) { myix = ixs[e]; myrk = rank[e]; }
    if (lane < 16) idxb[g * K_NE + myrk] = myix;

    // ---- edge rows: [sender_feat(128) | recv_feat(128)] -------------------
    const float* srow = S + (size_t)g * F;
    const float* rbase = Rv + (size_t)bz * N * F;
    float4 vs = {0.f, 0.f, 0.f, 0.f};
    if (lane < 32) vs = *(const float4*)(srow + lane * 4);
    #pragma unroll
    for (int e = 0; e < 16; ++e) {
        float4 vv = vs;
        if (lane >= 32)
            vv = *(const float4*)(rbase + (size_t)ixs[e] * F + (lane - 32) * 4);
        *(float4*)(edges_out + ((size_t)g * K_NE + rank[e]) * 256 + lane * 4) = vv;
    }
}

// ---------------- K2: build connectivity matrix (r4-proven) -----------------
__global__ __launch_bounds__(256) void conn_kernel(const int* __restrict__ idxb,
                                                   float* __restrict__ sm) {
    const int g = blockIdx.x;            // sender id 0..16383
    const int t = threadIdx.x;
    __shared__ int sidx[K_NE];
    if (t < K_NE) sidx[t] = idxb[g * K_NE + t];
    __syncthreads();
    float4 v0 = {0.f, 0.f, 0.f, 0.f}, v1 = {0.f, 0.f, 0.f, 0.f};
    #pragma unroll
    for (int k = 0; k < K_NE; ++k) {
        const int c = sidx[k];
        const int q = c >> 2, r = c & 3;
        if (q == t)       ((float*)&v0)[r] = 1.0f;
        if (q == t + 256) ((float*)&v1)[r] = 1.0f;
    }
    float4* orow = (float4*)(sm + (size_t)g * N);
    orow[t]       = v0;
    orow[t + 256] = v1;
}

extern "C" void kernel_launch(void* const* d_in, const int* in_sizes, int n_in,
                              void* d_out, int out_size, void* d_ws, size_t ws_size,
                              hipStream_t stream) {
    (void)in_sizes; (void)n_in; (void)out_size; (void)ws_size;
    const float* recv = (const float*)d_in[0];
    const float* send = (const float*)d_in[1];
    float* out = (float*)d_out;
    float* conn = out + EDGE_FLOATS;
    int*   idx_ws = (int*)d_ws;                       // 1 MB
    float* x2 = (float*)((char*)d_ws + (262144u * 4));
    float* y2 = x2 + NSEND;

    // f16 hi/lo staging at the head of the CONN region: dead during prep and
    // fused (which writes only edges + idx); conn_kernel overwrites it last.
    _Float16* SH = (_Float16*)conn;
    _Float16* SL = SH + HALF_ELEMS;
    _Float16* RH = SL + HALF_ELEMS;
    _Float16* RL = RH + HALF_ELEMS;                   // 16.8 MB << 128 MB

    prep_kernel<<<8192, 256, 0, stream>>>(send, recv, x2, y2, SH, SL, RH, RL);
    fused_kernel<<<1024, 1024, 0, stream>>>(send, recv, SH, SL, RH, RL,
                                            x2, y2, out, idx_ws);
    conn_kernel<<<16384, 256, 0, stream>>>(idx_ws, conn);
}

// Round 25
// 156.301 us; speedup vs baseline: 1.6456x; 1.6456x over previous
//
#include <hip/hip_runtime.h>
#include <cstdint>

#define K_NE 16
constexpr int B = 8, N = 2048, F = 128;
constexpr size_t NSEND = (size_t)B * N;                 // 16384 sender rows
constexpr size_t EDGE_FLOATS = NSEND * K_NE * 256;      // 67,108,864
constexpr size_t SEND_FLOATS = (size_t)B * N * N;       // 33,554,432

typedef _Float16 half8 __attribute__((ext_vector_type(8)));
typedef _Float16 half2v __attribute__((ext_vector_type(2)));
typedef float floatx4 __attribute__((ext_vector_type(4)));

#define SCALE 2048.0f                    // exact power of 2
#define INV_SC2 2.384185791015625e-07f   // 2^-22, exact
#define F16_MIN_NORM 6.103515625e-05f    // 2^-14

// ------------ K0: fused row norms + f32 -> scaled (f16 hi,lo) convert -------
__global__ __launch_bounds__(256) void prep_kernel(const float* __restrict__ S,
                                                   const float* __restrict__ Rv,
                                                   float* __restrict__ x2,
                                                   float* __restrict__ y2,
                                                   _Float16* __restrict__ SH,
                                                   _Float16* __restrict__ SL,
                                                   _Float16* __restrict__ RH,
                                                   _Float16* __restrict__ RL) {
    const int tid = blockIdx.x * 256 + threadIdx.x;
    const int w = tid >> 6, lane = tid & 63;           // w = 0..32767
    const bool isR = w >= (int)NSEND;
    const int row = isR ? w - (int)NSEND : w;
    const float* X = isR ? Rv : S;
    _Float16* H = isR ? RH : SH;
    _Float16* L = isR ? RL : SL;
    float* nrm = isR ? y2 : x2;

    const float2 v = ((const float2*)(X + (size_t)row * F))[lane];
    float s = v.x * v.x + v.y * v.y;
    #pragma unroll
    for (int off = 32; off; off >>= 1) s += __shfl_xor(s, off);
    if (lane == 0) nrm[row] = s;

    const float a0 = v.x * SCALE, a1 = v.y * SCALE;
    _Float16 h0 = (_Float16)a0;
    if (fabsf((float)h0) < F16_MIN_NORM) h0 = (_Float16)0.0f;
    _Float16 l0 = (_Float16)(a0 - (float)h0);
    if (fabsf((float)l0) < F16_MIN_NORM) l0 = (_Float16)0.0f;
    _Float16 h1 = (_Float16)a1;
    if (fabsf((float)h1) < F16_MIN_NORM) h1 = (_Float16)0.0f;
    _Float16 l1 = (_Float16)(a1 - (float)h1);
    if (fabsf((float)l1) < F16_MIN_NORM) l1 = (_Float16)0.0f;
    half2v hv = {h0, h1}, lv = {l0, l1};
    *(half2v*)(H + (size_t)row * F + lane * 2) = hv;
    *(half2v*)(L + (size_t)row * F + lane * 2) = lv;
}

// ---------------- K1: MFMA score matrix (frozen r17) ------------------------
__global__ __launch_bounds__(512) void score_mfma_kernel(
        const _Float16* __restrict__ SH, const _Float16* __restrict__ SL,
        const _Float16* __restrict__ RH, const _Float16* __restrict__ RL,
        const float* __restrict__ x2, const float* __restrict__ y2,
        float* __restrict__ scores) {
    __shared__ __attribute__((aligned(16))) _Float16 lA[2][2][4][128][8]; // 32 KB
    __shared__ __attribute__((aligned(16))) _Float16 lB[2][2][4][128][8]; // 32 KB
    const int bx = blockIdx.x, by = blockIdx.y, bz = blockIdx.z;
    const int t = threadIdx.x, lane = t & 63, wv = t >> 6;   // wv 0..7
    const int wrow0 = (wv >> 2) * 64;      // 0 or 64
    const int wcol0 = (wv & 3) * 32;       // 0,32,64,96
    const int lr = lane & 15, kg = lane >> 4;

    int s_h[2], s_kg[2], s_row[2];
    #pragma unroll
    for (int i = 0; i < 2; ++i) {
        const int s = t + (i << 9);
        s_h[i]   = s >> 9;
        s_row[i] = (s & 511) >> 2;
        s_kg[i]  = s & 3;
    }
    const size_t baseA = (size_t)(bz * N + by * 128);
    const size_t baseB = (size_t)(bz * N + bx * 128);

    #pragma unroll
    for (int i = 0; i < 2; ++i) {
        const _Float16* sa = (s_h[i] ? SL : SH) + (baseA + s_row[i]) * F + s_kg[i] * 8;
        const _Float16* sb = (s_h[i] ? RL : RH) + (baseB + s_row[i]) * F + s_kg[i] * 8;
        *(half8*)&lA[0][s_h[i]][s_kg[i]][s_row[i]][0] = *(const half8*)sa;
        *(half8*)&lB[0][s_h[i]][s_kg[i]][s_row[i]][0] = *(const half8*)sb;
    }
    __syncthreads();

    floatx4 acc[4][2] = {};

    #pragma unroll
    for (int kc = 0; kc < 4; ++kc) {    // 4 chunks of BK=32
        const int cur = kc & 1;
        half8 pa[2], pb[2];
        if (kc < 3) {
            const int ko = (kc + 1) * 32;
            #pragma unroll
            for (int i = 0; i < 2; ++i) {
                pa[i] = *(const half8*)((s_h[i] ? SL : SH) + (baseA + s_row[i]) * F + ko + s_kg[i] * 8);
                pb[i] = *(const half8*)((s_h[i] ? RL : RH) + (baseB + s_row[i]) * F + ko + s_kg[i] * 8);
            }
        }
        half8 ah[4], al[4];
        #pragma unroll
        for (int i = 0; i < 4; ++i) {
            ah[i] = *(const half8*)&lA[cur][0][kg][wrow0 + i * 16 + lr][0];
            al[i] = *(const half8*)&lA[cur][1][kg][wrow0 + i * 16 + lr][0];
        }
        #pragma unroll
        for (int j = 0; j < 2; ++j) {
            const half8 bh = *(const half8*)&lB[cur][0][kg][wcol0 + j * 16 + lr][0];
            const half8 bl = *(const half8*)&lB[cur][1][kg][wcol0 + j * 16 + lr][0];
            #pragma unroll
            for (int i = 0; i < 4; ++i) {
                acc[i][j] = __builtin_amdgcn_mfma_f32_16x16x32_f16(ah[i], bh, acc[i][j], 0, 0, 0);
                acc[i][j] = __builtin_amdgcn_mfma_f32_16x16x32_f16(ah[i], bl, acc[i][j], 0, 0, 0);
                acc[i][j] = __builtin_amdgcn_mfma_f32_16x16x32_f16(al[i], bh, acc[i][j], 0, 0, 0);
            }
        }
        if (kc < 3) {
            const int nxt = cur ^ 1;
            #pragma unroll
            for (int i = 0; i < 2; ++i) {
                *(half8*)&lA[nxt][s_h[i]][s_kg[i]][s_row[i]][0] = pa[i];
                *(half8*)&lB[nxt][s_h[i]][s_kg[i]][s_row[i]][0] = pb[i];
            }
            __syncthreads();
        }
    }

    float* outb = scores + (size_t)bz * N * N;
    const float* x2b = x2 + (size_t)bz * N;
    const float* y2b = y2 + (size_t)bz * N;
    #pragma unroll
    for (int j = 0; j < 2; ++j) {
        const int col = bx * 128 + wcol0 + j * 16 + lr;
        const float yv = y2b[col];
        #pragma unroll
        for (int i = 0; i < 4; ++i) {
            #pragma unroll
            for (int r = 0; r < 4; ++r) {
                const int row = by * 128 + wrow0 + i * 16 + (lane >> 4) * 4 + r;
                const float d = acc[i][j][r] * INV_SC2;   // exact unscale
                outb[(size_t)row * N + col] = fabsf((-2.0f * d + x2b[row]) + yv);
            }
        }
    }
}

#define KEYC(U, C) ((C) == 0 ? (U).x : (C) == 1 ? (U).y : (C) == 2 ? (U).z : (U).w)

// ------- K2: fused top-16, fully register-resident row (r18 record) ---------
__global__ __launch_bounds__(256) void topk_fused_kernel(const float* __restrict__ S,
                                                         const float* __restrict__ Rv,
                                                         float* __restrict__ scores,
                                                         float* __restrict__ edges_out) {
    __shared__ double candbuf[4][64];     // 2 KB candidate buffers
    const int t = threadIdx.x;
    const int lane = t & 63;
    const int w = t >> 6;
    const int g = blockIdx.x * 4 + w;     // global sender id 0..16383
    const int bz = g >> 11;               // batch
    double* cbuf = candbuf[w];
    float* srowp = scores + (size_t)g * N;
    const uint4* sr = (const uint4*)srowp;
    const double MAGIC = 4503599627370496.0;   // 2^52

    // ---- load row into registers; per-lane value-min ----------------------
    uint4 u[8];
    uint32_t mk = 0xFFFFFFFFu;
    #pragma unroll
    for (int jj = 0; jj < 8; ++jj) {
        u[jj] = sr[jj * 64 + lane];
        mk = mk < u[jj].x ? mk : u[jj].x;
        mk = mk < u[jj].y ? mk : u[jj].y;
        mk = mk < u[jj].z ? mk : u[jj].z;
        mk = mk < u[jj].w ? mk : u[jj].w;
    }

    // ---- bitonic sort of lane-mins (ascending) -> T16 = sorted[15] --------
    uint32_t v = mk;
    #pragma unroll
    for (int k = 2; k <= 64; k <<= 1) {
        #pragma unroll
        for (int j = k >> 1; j >= 1; j >>= 1) {
            uint32_t o = (uint32_t)__shfl_xor((int)v, j);
            const bool take_min = (((lane & j) == 0) == ((lane & k) == 0));
            const uint32_t mn = v < o ? v : o;
            const uint32_t mx = v < o ? o : v;
            v = take_min ? mn : mx;
        }
    }
    const uint32_t T16 = (uint32_t)__shfl((int)v, 15);

    // ---- per-lane candidate count + prefix-sum offsets --------------------
    int myc = 0;
    #pragma unroll
    for (int jj = 0; jj < 8; ++jj)
        #pragma unroll
        for (int c = 0; c < 4; ++c)
            myc += (KEYC(u[jj], c) <= T16) ? 1 : 0;
    int off = myc;
    #pragma unroll
    for (int d = 1; d < 64; d <<= 1) {
        const int o = __shfl_up(off, d);
        if (lane >= d) off += o;
    }
    const int total = __shfl(off, 63);
    const int base = off - myc;

    int ixs[16];
    if (total <= 64) {
        int p = base;
        #pragma unroll
        for (int jj = 0; jj < 8; ++jj)
            #pragma unroll
            for (int c = 0; c < 4; ++c) {
                const uint32_t key = KEYC(u[jj], c);
                if (key <= T16) {
                    cbuf[p] = (double)key * 2048.0 + (double)(jj * 256 + lane * 4 + c);
                    ++p;
                }
            }
        double d = (lane < total) ? cbuf[lane] : 1e300;
        #pragma unroll
        for (int k = 2; k <= 64; k <<= 1) {
            #pragma unroll
            for (int j = k >> 1; j >= 1; j >>= 1) {
                const double o = __shfl_xor(d, j);
                const bool take_min = (((lane & j) == 0) == ((lane & k) == 0));
                d = take_min ? fmin(d, o) : fmax(d, o);
            }
        }
        const int myidx = (int)(__double_as_longlong(d + MAGIC) & 2047);
        #pragma unroll
        for (int e = 0; e < 16; ++e) ixs[e] = __shfl(myidx, e);
    } else {
        // ---- fallback (tie storm): register-masked iterative extraction --
        uint32_t fk = 0xFFFFFFFFu, fi = 0;
        #pragma unroll
        for (int jj = 0; jj < 8; ++jj) {
            const uint32_t bse = (uint32_t)(jj * 256 + lane * 4);
            if (u[jj].x < fk) { fk = u[jj].x; fi = bse; }
            if (u[jj].y < fk) { fk = u[jj].y; fi = bse + 1; }
            if (u[jj].z < fk) { fk = u[jj].z; fi = bse + 2; }
            if (u[jj].w < fk) { fk = u[jj].w; fi = bse + 3; }
        }
        #pragma unroll
        for (int it = 0; it < 16; ++it) {
            const uint32_t ck = fk, ci = fi;
            uint32_t gk = fk, gi = fi;
            #pragma unroll
            for (int o2 = 32; o2; o2 >>= 1) {
                uint32_t ok = (uint32_t)__shfl_xor((int)gk, o2);
                uint32_t oi = (uint32_t)__shfl_xor((int)gi, o2);
                if (ok < gk || (ok == gk && oi < gi)) { gk = ok; gi = oi; }
            }
            ixs[it] = (int)gi;
            if (ck == gk && ci == gi) {       // owner deletes own register
                const int djj = (int)(gi >> 8), dc = (int)(gi & 3);
                #pragma unroll
                for (int jj = 0; jj < 8; ++jj)
                    if (jj == djj) {
                        if (dc == 0) u[jj].x = 0xFFFFFFFFu;
                        else if (dc == 1) u[jj].y = 0xFFFFFFFFu;
                        else if (dc == 2) u[jj].z = 0xFFFFFFFFu;
                        else u[jj].w = 0xFFFFFFFFu;
                    }
                fk = 0xFFFFFFFFu; fi = 0;
                #pragma unroll
                for (int jj = 0; jj < 8; ++jj) {
                    const uint32_t bse = (uint32_t)(jj * 256 + lane * 4);
                    if (u[jj].x < fk) { fk = u[jj].x; fi = bse; }
                    if (u[jj].y < fk) { fk = u[jj].y; fi = bse + 1; }
                    if (u[jj].z < fk) { fk = u[jj].z; fi = bse + 2; }
                    if (u[jj].w < fk) { fk = u[jj].w; fi = bse + 3; }
                }
            }
        }
    }

    // ---- ranks: output slot = ascending receiver-index position -----------
    int rank[16];
    #pragma unroll
    for (int e = 0; e < 16; ++e) {
        int r = 0;
        #pragma unroll
        for (int f = 0; f < 16; ++f) r += (ixs[f] < ixs[e]) ? 1 : 0;
        rank[e] = r;
    }

    // ---- connectivity row (overwrites this wave's score row) --------------
    uint32_t mask = 0;
    #pragma unroll
    for (int e = 0; e < 16; ++e) {
        const int ix = ixs[e];
        const int lane_t = (ix >> 2) & 63;
        const int bitpos = ((ix >> 8) << 2) | (ix & 3);
        if (lane == lane_t) mask |= (1u << bitpos);
    }
    #pragma unroll
    for (int j = 0; j < 8; ++j) {
        float4 vv;
        vv.x = (mask >> (j * 4 + 0)) & 1u ? 1.f : 0.f;
        vv.y = (mask >> (j * 4 + 1)) & 1u ? 1.f : 0.f;
        vv.z = (mask >> (j * 4 + 2)) & 1u ? 1.f : 0.f;
        vv.w = (mask >> (j * 4 + 3)) & 1u ? 1.f : 0.f;
        *(float4*)(srowp + j * 256 + lane * 4) = vv;
    }

    // ---- edge rows: [sender_feat(128) | recv_feat(128)] -------------------
    const float* srow = S + (size_t)g * F;
    const float* rb = Rv + (size_t)bz * N * F;
    float4 vs = {0.f, 0.f, 0.f, 0.f};
    if (lane < 32) vs = *(const float4*)(srow + lane * 4);
    #pragma unroll
    for (int e = 0; e < 16; ++e) {
        float4 vv = vs;
        if (lane >= 32)
            vv = *(const float4*)(rb + (size_t)ixs[e] * F + (lane - 32) * 4);
        *(float4*)(edges_out + ((size_t)g * K_NE + rank[e]) * 256 + lane * 4) = vv;
    }
}

extern "C" void kernel_launch(void* const* d_in, const int* in_sizes, int n_in,
                              void* d_out, int out_size, void* d_ws, size_t ws_size,
                              hipStream_t stream) {
    (void)in_sizes; (void)n_in; (void)out_size; (void)ws_size;
    const float* recv = (const float*)d_in[0];
    const float* send = (const float*)d_in[1];
    float* out = (float*)d_out;
    float* sender_mat = out + EDGE_FLOATS;       // score scratch, then conn matrix
    float* x2 = (float*)((char*)d_ws + (262144u * 4));
    float* y2 = x2 + NSEND;

    // f16 hi/lo staging lives in the edges region (dead until topk_fused).
    _Float16* SH = (_Float16*)out;
    _Float16* SL = SH + NSEND * F;
    _Float16* RH = SL + NSEND * F;
    _Float16* RL = RH + NSEND * F;               // total 16.8 MB << 256 MB

    prep_kernel<<<8192, 256, 0, stream>>>(send, recv, x2, y2, SH, SL, RH, RL);
    dim3 g1(16, 16, 8);
    score_mfma_kernel<<<g1, 512, 0, stream>>>(SH, SL, RH, RL, x2, y2, sender_mat);
    topk_fused_kernel<<<4096, 256, 0, stream>>>(send, recv, sender_mat, out);
}